// Round 7
// baseline (2000.246 us; speedup 1.0000x reference)
//
#include <hip/hip_runtime.h>
#include <stdint.h>

#define NUMA 3
#define NUMC 80
#define CAP  32768
#define KTOP 400
#define POST 100
#define NBIN1 2048
#define EQCAP 1024
#define KEY0 0x3EE66666u   // __float_as_uint(0.45f): static compact threshold

typedef float f32x4 __attribute__((ext_vector_type(4)));

__device__ __forceinline__ float sigmoidf_(float x) { return 1.0f / (1.0f + expf(-x)); }
__device__ __forceinline__ unsigned uminu(unsigned a, unsigned b) { return a < b ? a : b; }

// async global->LDS staging (wave-uniform LDS base + lane*size)
__device__ __forceinline__ void load_lds16(const void* g, void* l) {
    __builtin_amdgcn_global_load_lds((const __attribute__((address_space(1))) void*)g,
                                     (__attribute__((address_space(3))) void*)l, 16, 0, 0);
}
__device__ __forceinline__ void load_lds4(const void* g, void* l) {
    __builtin_amdgcn_global_load_lds((const __attribute__((address_space(1))) void*)g,
                                     (__attribute__((address_space(3))) void*)l, 4, 0, 0);
}

// ---------------- init: zero hist + cutb + ccnt + flags --------------------
__global__ void init_kernel(unsigned* __restrict__ p) {
    int i = blockIdx.x * blockDim.x + threadIdx.x;
    if (i < NBIN1 * 8 + 24) p[i] = 0;
}

// ---------------- ballot-aggregated emit (static threshold) ----------------
__device__ __forceinline__ void emit_agg(float sc, unsigned idx, int b,
        unsigned* ccnt, unsigned* ckey, unsigned* cidx)
{
    unsigned key = __float_as_uint(sc);
    unsigned long long mask = __ballot(key >= KEY0);
    if (mask != 0ull) {
        if (key >= KEY0) {
            int lane = threadIdx.x & 63;
            int rank = __popcll(mask & ((1ull << lane) - 1ull));
            int total = __popcll(mask);
            int leader = __ffsll((long long)mask) - 1;
            unsigned base = 0;
            if (lane == leader) base = atomicAdd(&ccnt[b], (unsigned)total);
            base = (unsigned)__shfl((int)base, leader);
            unsigned pos = base + (unsigned)rank;
            if (pos < CAP) {
                ckey[(size_t)b * CAP + pos] = key;
                cidx[(size_t)b * CAP + pos] = idx;
            }
        }
    }
}

// ---------------- main pass: async-LDS-staged decode + compact -------------
// grid (10, 10, 24): x = hw-chunk (0-1: t0 scalar; 2-3: t1 vec; 4-9: t2 vec),
// y = class-group (8 classes), z = b*3 + a. Each wave issues 9 async
// global_load_lds stages (structural MLP=9), one barrier drains all.
__global__ __launch_bounds__(256) void score_main(
        const float* __restrict__ t0, const float* __restrict__ t1,
        const float* __restrict__ t2,
        unsigned* __restrict__ ccnt, unsigned* __restrict__ ckey,
        unsigned* __restrict__ cidx)
{
    __shared__ __align__(16) float s_conf[1024];
    __shared__ __align__(16) float s_cls[8][1024];
    const int tid = threadIdx.x;
    const int wv = tid >> 6, ln = tid & 63;
    const int ba = blockIdx.z;
    const int b = ba / 3, a = ba - 3 * b;
    const int c0 = blockIdx.y * 8;
    const int cx = blockIdx.x;

    if (cx < 2) {
        // ---- t0: HW=361, scalar staging (plane stride not 16B-aligned) ----
        const float* base = t0 + (size_t)(b * 255 + a * 85) * 361;
        const int hw0 = cx * 256;
        int hw = hw0 + wv * 64 + ln;
        bool act = hw < 361;
        if (act) load_lds4(base + 4 * 361 + hw, &s_conf[wv * 64]);
        #pragma unroll
        for (int u = 0; u < 8; u++)
            if (act) load_lds4(base + (size_t)(5 + c0 + u) * 361 + hw, &s_cls[u][wv * 64]);
        __syncthreads();
        int hwt = hw0 + tid;
        float cf = 0.f;
        bool on = hwt < 361;
        if (on) cf = sigmoidf_(s_conf[tid]);
        unsigned ib = (unsigned)((hwt * NUMA + a) * NUMC + c0);
        #pragma unroll
        for (int u = 0; u < 8; u++) {
            float sc = on ? sigmoidf_(s_cls[u][tid]) * cf : 0.f;
            emit_agg(sc, ib + (unsigned)u, b, ccnt, ckey, cidx);
        }
    } else {
        // ---- t1/t2: float4 staging ----
        const float* tip; int vHW, vbase, candOff;
        if (cx < 4) { tip = t1; vHW = 361;  vbase = (cx - 2) * 256; candOff = 86640; }
        else        { tip = t2; vHW = 1444; vbase = (cx - 4) * 256; candOff = 433200; }
        const f32x4* bp = (const f32x4*)(tip + (size_t)(b * 255 + a * 85) * (size_t)(vHW * 4));
        int v = vbase + wv * 64 + ln;
        bool act = v < vHW;
        if (act) load_lds16(bp + (size_t)4 * vHW + v, &s_conf[(wv * 64) * 4]);
        #pragma unroll
        for (int u = 0; u < 8; u++)
            if (act) load_lds16(bp + (size_t)(5 + c0 + u) * vHW + v, &s_cls[u][(wv * 64) * 4]);
        __syncthreads();
        int vt = vbase + tid;
        bool on = vt < vHW;
        float cf0 = 0.f, cf1 = 0.f, cf2 = 0.f, cf3 = 0.f;
        if (on) {
            f32x4 cv = *(const f32x4*)&s_conf[tid * 4];
            cf0 = sigmoidf_(cv[0]); cf1 = sigmoidf_(cv[1]);
            cf2 = sigmoidf_(cv[2]); cf3 = sigmoidf_(cv[3]);
        }
        unsigned ib0 = (unsigned)(candOff + (vt * 4 * NUMA + a) * NUMC + c0);
        #pragma unroll
        for (int u = 0; u < 8; u++) {
            float s0 = 0.f, s1 = 0.f, s2 = 0.f, s3 = 0.f;
            if (on) {
                f32x4 s = *(const f32x4*)&s_cls[u][tid * 4];
                s0 = sigmoidf_(s[0]) * cf0; s1 = sigmoidf_(s[1]) * cf1;
                s2 = sigmoidf_(s[2]) * cf2; s3 = sigmoidf_(s[3]) * cf3;
            }
            unsigned ib = ib0 + (unsigned)u;
            emit_agg(s0, ib,       b, ccnt, ckey, cidx);
            emit_agg(s1, ib + 240, b, ccnt, ckey, cidx);
            emit_agg(s2, ib + 480, b, ccnt, ckey, cidx);
            emit_agg(s3, ib + 720, b, ccnt, ckey, cidx);
        }
    }
}

// ---------------- validate static cut --------------------------------------
__global__ void validate_kernel(unsigned* __restrict__ ccnt, unsigned* __restrict__ flags) {
    int b = threadIdx.x;
    if (b < 8) {
        unsigned c = ccnt[b];
        bool ok = (c >= KTOP) && (c <= CAP);
        flags[b] = ok ? 1u : 0u;
        if (!ok) ccnt[b] = 0;
    }
}

// ---------------- fallback: full histogram (early-exits when valid) --------
__global__ __launch_bounds__(256) void fb_hist(
        const float* __restrict__ t0, const float* __restrict__ t1,
        const float* __restrict__ t2,
        unsigned* __restrict__ hist, const unsigned* __restrict__ flags)
{
    const int ba = blockIdx.z;
    const int b = ba / 3, a = ba - 3 * b;
    if (flags[b]) return;
    __shared__ unsigned lh[NBIN1];
    const int tid = threadIdx.x;
    for (int i = tid; i < NBIN1; i += 256) lh[i] = 0;
    __syncthreads();
    const int c0 = blockIdx.y * 8;
    const int cx = blockIdx.x;
    if (cx < 2) {
        const int hw = cx * 256 + tid;
        if (hw < 361) {
            const float* base = t0 + (size_t)(b * 255 + a * 85) * 361;
            float cf = sigmoidf_(base[4 * 361 + hw]);
            for (int u = 0; u < 8; u++) {
                float sc = sigmoidf_(base[(size_t)(5 + c0 + u) * 361 + hw]) * cf;
                atomicAdd(&lh[__float_as_uint(sc) >> 19], 1u);
            }
        }
    } else {
        const float* tip; int vHW, v;
        if (cx < 4) { tip = t1; vHW = 361;  v = (cx - 2) * 256 + tid; }
        else        { tip = t2; vHW = 1444; v = (cx - 4) * 256 + tid; }
        if (v < vHW) {
            const f32x4* bp = (const f32x4*)(tip + (size_t)(b * 255 + a * 85) * (size_t)(vHW * 4));
            f32x4 cv = bp[(size_t)4 * vHW + v];
            float cf[4] = { sigmoidf_(cv[0]), sigmoidf_(cv[1]), sigmoidf_(cv[2]), sigmoidf_(cv[3]) };
            for (int u = 0; u < 8; u++) {
                f32x4 s = bp[(size_t)(5 + c0 + u) * vHW + v];
                for (int l = 0; l < 4; l++)
                    atomicAdd(&lh[__float_as_uint(sigmoidf_(s[l]) * cf[l]) >> 19], 1u);
            }
        }
    }
    __syncthreads();
    unsigned* gh = hist + b * NBIN1;
    for (int i = tid; i < NBIN1; i += 256) {
        unsigned v2 = lh[i];
        if (v2) atomicAdd(&gh[i], v2);
    }
}

// ---------------- wave-parallel rank select over an LDS histogram ----------
__device__ __forceinline__ void wave_select(const unsigned* h, int nbins, unsigned rank,
                                            unsigned* resv, int tid)
{
    if (tid >= 64) return;
    const int lane = tid;
    const int cs = nbins >> 6;
    unsigned v = 0;
    for (int k = 0; k < cs; k++) {
        int off = (k + lane) & (cs - 1);
        v += h[lane * cs + off];
    }
    unsigned S = v;
    #pragma unroll
    for (int o = 1; o < 64; o <<= 1) {
        unsigned t = (unsigned)__shfl_down((int)S, o);
        if (lane + o < 64) S += t;
    }
    unsigned long long bm = __ballot(S >= rank);
    int C = 63 - __builtin_clzll(bm);
    unsigned SC = (unsigned)__builtin_amdgcn_readlane((int)S, C);
    unsigned vC = (unsigned)__builtin_amdgcn_readlane((int)v, C);
    unsigned rem = rank - (SC - vC);
    unsigned w = (lane < cs) ? h[C * cs + lane] : 0u;
    unsigned T = w;
    #pragma unroll
    for (int o = 1; o < 64; o <<= 1) {
        unsigned t = (unsigned)__shfl_down((int)T, o);
        if (lane + o < 64) T += t;
    }
    unsigned long long bm2 = __ballot((T >= rem) && (lane < cs));
    int B = 63 - __builtin_clzll(bm2);
    unsigned TB = (unsigned)__builtin_amdgcn_readlane((int)T, B);
    unsigned wB = (unsigned)__builtin_amdgcn_readlane((int)w, B);
    if (lane == 0) {
        resv[0] = (unsigned)(C * cs + B);
        resv[1] = rem - (TB - wB);
    }
}

// ---------------- fallback: find rank-400 bin ------------------------------
__global__ __launch_bounds__(256) void fb_cut(const unsigned* __restrict__ hist,
                                              unsigned* __restrict__ cutb,
                                              const unsigned* __restrict__ flags) {
    int b = blockIdx.x;
    if (flags[b]) return;
    __shared__ unsigned h[NBIN1];
    __shared__ unsigned resv[2];
    for (int i = threadIdx.x; i < NBIN1; i += 256) h[i] = hist[b * NBIN1 + i];
    __syncthreads();
    wave_select(h, NBIN1, KTOP, resv, threadIdx.x);
    __syncthreads();
    if (threadIdx.x == 0) cutb[b] = resv[0];
}

// ---------------- fallback: recompact with exact bin cut -------------------
__global__ __launch_bounds__(256) void fb_compact(
        const float* __restrict__ t0, const float* __restrict__ t1,
        const float* __restrict__ t2,
        const unsigned* __restrict__ cutb, unsigned* __restrict__ ccnt,
        unsigned* __restrict__ ckey, unsigned* __restrict__ cidx,
        const unsigned* __restrict__ flags)
{
    const int ba = blockIdx.z;
    const int b = ba / 3, a = ba - 3 * b;
    if (flags[b]) return;
    const int tid = threadIdx.x;
    const int c0 = blockIdx.y * 8;
    const int cx = blockIdx.x;
    unsigned cutkey = cutb[b] << 19;

    if (cx < 2) {
        const int hw = cx * 256 + tid;
        if (hw < 361) {
            const float* base = t0 + (size_t)(b * 255 + a * 85) * 361;
            float cf = sigmoidf_(base[4 * 361 + hw]);
            for (int u = 0; u < 8; u++) {
                float sc = sigmoidf_(base[(size_t)(5 + c0 + u) * 361 + hw]) * cf;
                unsigned key = __float_as_uint(sc);
                if (key >= cutkey) {
                    unsigned pos = atomicAdd(&ccnt[b], 1u);
                    if (pos < CAP) {
                        ckey[(size_t)b * CAP + pos] = key;
                        cidx[(size_t)b * CAP + pos] = (unsigned)((hw * NUMA + a) * NUMC + c0 + u);
                    }
                }
            }
        }
    } else {
        const float* tip; int vHW, v, candOff;
        if (cx < 4) { tip = t1; vHW = 361;  v = (cx - 2) * 256 + tid; candOff = 86640; }
        else        { tip = t2; vHW = 1444; v = (cx - 4) * 256 + tid; candOff = 433200; }
        if (v < vHW) {
            const f32x4* bp = (const f32x4*)(tip + (size_t)(b * 255 + a * 85) * (size_t)(vHW * 4));
            f32x4 cv = bp[(size_t)4 * vHW + v];
            float cf[4] = { sigmoidf_(cv[0]), sigmoidf_(cv[1]), sigmoidf_(cv[2]), sigmoidf_(cv[3]) };
            unsigned ib0 = (unsigned)(candOff + (v * 4 * NUMA + a) * NUMC + c0);
            for (int u = 0; u < 8; u++) {
                f32x4 s = bp[(size_t)(5 + c0 + u) * vHW + v];
                for (int l = 0; l < 4; l++) {
                    float sc = sigmoidf_(s[l]) * cf[l];
                    unsigned key = __float_as_uint(sc);
                    if (key >= cutkey) {
                        unsigned pos = atomicAdd(&ccnt[b], 1u);
                        if (pos < CAP) {
                            ckey[(size_t)b * CAP + pos] = key;
                            cidx[(size_t)b * CAP + pos] = ib0 + (unsigned)u + (unsigned)l * 240;
                        }
                    }
                }
            }
        }
    }
}

// ---------------- per-image: exact top-400, NMS, output --------------------
__global__ __launch_bounds__(512) void nms_kernel(
        const float* __restrict__ t0, const float* __restrict__ t1,
        const float* __restrict__ t2,
        const float* __restrict__ anc0, const float* __restrict__ anc1,
        const float* __restrict__ anc2,
        const unsigned* __restrict__ ckey, const unsigned* __restrict__ cidx,
        const unsigned* __restrict__ ccnt, float* __restrict__ out)
{
    const int b = blockIdx.x;
    const int tid = threadIdx.x;
    const int T = 512;

    __shared__ unsigned hist[4096];
    __shared__ unsigned resv[2];
    __shared__ unsigned selk[512], seli[512];
    __shared__ unsigned eqi[EQCAP];
    __shared__ float sx1[KTOP], sy1[KTOP], sx2[KTOP], sy2[KTOP], ssc[KTOP];
    __shared__ int   scid[KTOP];
    __shared__ unsigned long long maskS[KTOP * 7];
    __shared__ unsigned long long vkeep[7];
    __shared__ unsigned cnts[2];
    __shared__ float oid[POST], osc[POST], obb[POST * 4];

    const unsigned n = uminu(ccnt[b], (unsigned)CAP);
    const unsigned* ck = ckey + (size_t)b * CAP;
    const unsigned* ci = cidx + (size_t)b * CAP;

    // ---- Round 1: bits [30:19] ----
    for (int i = tid; i < NBIN1; i += T) hist[i] = 0;
    __syncthreads();
    for (unsigned i = tid; i < n; i += T) atomicAdd(&hist[ck[i] >> 19], 1u);
    __syncthreads();
    wave_select(hist, NBIN1, KTOP, resv, tid);
    __syncthreads();
    unsigned b1 = resv[0], r2 = resv[1];
    __syncthreads();

    // ---- Round 2: bits [18:7] ----
    for (int i = tid; i < 4096; i += T) hist[i] = 0;
    __syncthreads();
    for (unsigned i = tid; i < n; i += T) {
        unsigned k = ck[i];
        if ((k >> 19) == b1) atomicAdd(&hist[(k >> 7) & 0xFFFu], 1u);
    }
    __syncthreads();
    wave_select(hist, 4096, r2, resv, tid);
    __syncthreads();
    unsigned b2 = resv[0], r3 = resv[1];
    __syncthreads();

    // ---- Round 3: bits [6:0] ----
    for (int i = tid; i < 128; i += T) hist[i] = 0;
    __syncthreads();
    unsigned pref = (b1 << 12) | b2;
    for (unsigned i = tid; i < n; i += T) {
        unsigned k = ck[i];
        if ((k >> 7) == pref) atomicAdd(&hist[k & 127u], 1u);
    }
    __syncthreads();
    wave_select(hist, 128, r3, resv, tid);
    __syncthreads();
    unsigned b3 = resv[0], needEq = resv[1];
    unsigned K400 = (b1 << 19) | (b2 << 7) | b3;
    __syncthreads();

    // ---- compaction ----
    selk[tid] = 0u; seli[tid] = 0xFFFFFFFFu;
    for (int i = tid; i < EQCAP; i += T) eqi[i] = 0xFFFFFFFFu;
    if (tid == 0) { cnts[0] = 0; cnts[1] = 0; }
    __syncthreads();
    for (unsigned i = tid; i < n; i += T) {
        unsigned k = ck[i];
        if (k > K400) {
            unsigned p = atomicAdd(&cnts[0], 1u);
            if (p < KTOP) { selk[p] = k; seli[p] = ci[i]; }
        } else if (k == K400) {
            unsigned q = atomicAdd(&cnts[1], 1u);
            if (q < EQCAP) eqi[q] = ci[i];
        }
    }
    __syncthreads();
    unsigned selCnt = uminu(cnts[0], (unsigned)KTOP);
    unsigned eqN   = uminu(cnts[1], (unsigned)EQCAP);

    // ---- tie list: only sort if we must pick a strict subset ----
    if (eqN > needEq) {
        int P2 = 1; while ((unsigned)P2 < eqN) P2 <<= 1;
        for (int k2 = 2; k2 <= P2; k2 <<= 1) {
            for (int j = k2 >> 1; j > 0; j >>= 1) {
                __syncthreads();
                for (int i = tid; i < P2; i += T) {
                    int ixj = i ^ j;
                    if (ixj > i && ixj < P2) {
                        unsigned va = eqi[i], vb = eqi[ixj];
                        bool up = ((i & k2) == 0);
                        if (up ? (va > vb) : (va < vb)) { eqi[i] = vb; eqi[ixj] = va; }
                    }
                }
            }
        }
        __syncthreads();
    }
    for (unsigned t2v = tid; t2v < needEq; t2v += T) {
        unsigned p = selCnt + t2v;
        if (p < KTOP) { selk[p] = K400; seli[p] = eqi[t2v]; }
    }
    __syncthreads();

    // ---- bitonic sort 512 by (key desc, idx asc); j<64 passes in-wave ----
    for (int k2 = 2; k2 <= 512; k2 <<= 1) {
        int j = k2 >> 1;
        for (; j >= 64; j >>= 1) {
            __syncthreads();
            int i = tid, ixj = i ^ j;
            if (ixj > i) {
                unsigned ka = selk[i], kb = selk[ixj], ia = seli[i], ib = seli[ixj];
                bool before = (ka > kb) || (ka == kb && ia < ib);
                bool up = ((i & k2) == 0);
                if (up ? !before : before) {
                    selk[i] = kb; selk[ixj] = ka; seli[i] = ib; seli[ixj] = ia;
                }
            }
        }
        __syncthreads();
        for (; j > 0; j >>= 1) {
            int i = tid, ixj = i ^ j;
            if (ixj > i) {
                unsigned ka = selk[i], kb = selk[ixj], ia = seli[i], ib = seli[ixj];
                bool before = (ka > kb) || (ka == kb && ia < ib);
                bool up = ((i & k2) == 0);
                if (up ? !before : before) {
                    selk[i] = kb; selk[ixj] = ka; seli[i] = ib; seli[ixj] = ia;
                }
            }
        }
    }
    __syncthreads();

    // ---- gather + on-the-fly box decode for the 400 selected ----
    if (tid < KTOP) {
        unsigned idx = seli[tid];
        const float* tip; const float* anc; int HW, W, candOff; float strideF;
        if (idx < 86640u)       { tip = t0; anc = anc0; HW = 361;  W = 19; strideF = 32.f; candOff = 0; }
        else if (idx < 433200u) { tip = t1; anc = anc1; HW = 1444; W = 38; strideF = 16.f; candOff = 86640; }
        else                    { tip = t2; anc = anc2; HW = 5776; W = 76; strideF = 8.f;  candOff = 433200; }
        unsigned local = idx - (unsigned)candOff;
        int cls = (int)(local % NUMC);
        int nn  = (int)(local / NUMC);
        int a = nn % NUMA, hwl = nn / NUMA;
        const float* base = tip + (size_t)(b * 255 + a * 85) * HW + hwl;
        float tx = base[0];
        float ty = base[(size_t)HW];
        float tw = base[(size_t)2 * HW];
        float th = base[(size_t)3 * HW];
        float fx = (float)(hwl % W), fy = (float)(hwl / W);
        float cx = (sigmoidf_(tx) + fx) * strideF;
        float cy = (sigmoidf_(ty) + fy) * strideF;
        float hw_ = expf(tw) * anc[2 * a]     * 0.5f;
        float hh_ = expf(th) * anc[2 * a + 1] * 0.5f;
        sx1[tid] = cx - hw_; sy1[tid] = cy - hh_;
        sx2[tid] = cx + hw_; sy2[tid] = cy + hh_;
        ssc[tid] = __uint_as_float(selk[tid]);
        scid[tid] = cls;
    }
    __syncthreads();

    // ---- suppression bitmasks ----
    for (int p = tid; p < KTOP * 7; p += T) {
        int i = p / 7, w = p - i * 7;
        float x1i = sx1[i], y1i = sy1[i], x2i = sx2[i], y2i = sy2[i];
        float ai = fmaxf(x2i - x1i, 0.f) * fmaxf(y2i - y1i, 0.f);
        int cidI = scid[i];
        unsigned long long m = 0ull;
        int j0 = w * 64;
        int j1 = j0 + 64; if (j1 > KTOP) j1 = KTOP;
        int js = j0 > i + 1 ? j0 : i + 1;
        for (int j = js; j < j1; j++) {
            if (scid[j] != cidI) continue;
            float iw = fminf(x2i, sx2[j]) - fmaxf(x1i, sx1[j]);
            float ih = fminf(y2i, sy2[j]) - fmaxf(y1i, sy1[j]);
            iw = fmaxf(iw, 0.f); ih = fmaxf(ih, 0.f);
            float inter = iw * ih;
            float aj = fmaxf(sx2[j] - sx1[j], 0.f) * fmaxf(sy2[j] - sy1[j], 0.f);
            float iou = inter / (ai + aj - inter + 1e-12f);
            if (iou > 0.45f) m |= (1ull << (j - j0));
        }
        maskS[p] = m;
    }
    __syncthreads();

    // ---- greedy NMS: keep words in lanes 0..6; v_readlane broadcast -------
    if (tid < 64) {
        unsigned long long keep = 0ull;
        if (tid < 7) keep = (tid == 6) ? 0xFFFFull : ~0ull;
        unsigned long long m = (tid < 7) ? maskS[tid] : 0ull;
        for (int i = 0; i < KTOP; i++) {
            unsigned long long mn = (tid < 7 && i + 1 < KTOP) ? maskS[(i + 1) * 7 + tid] : 0ull;
            int w = i >> 6;
            unsigned klo = (unsigned)__builtin_amdgcn_readlane((int)(unsigned)(keep & 0xFFFFFFFFull), w);
            unsigned khi = (unsigned)__builtin_amdgcn_readlane((int)(unsigned)(keep >> 32), w);
            unsigned long long kw = ((unsigned long long)khi << 32) | klo;
            if ((kw >> (i & 63)) & 1ull) keep &= ~m;
            m = mn;
        }
        if (tid < 7) vkeep[tid] = keep;
    }
    __syncthreads();

    // ---- emit top-100, pad -1 ----
    if (tid < POST) { oid[tid] = -1.f; osc[tid] = -1.f; }
    if (tid < POST * 4) obb[tid] = -1.f;
    __syncthreads();
    if (tid < KTOP) {
        int w = tid >> 6, bp = tid & 63;
        unsigned long long kw = vkeep[w];
        if ((kw >> bp) & 1ull) {
            int r = 0;
            for (int q = 0; q < w; q++) r += __popcll(vkeep[q]);
            r += __popcll(kw & ((1ull << bp) - 1ull));
            if (r < POST) {
                oid[r] = (float)scid[tid];
                osc[r] = ssc[tid];
                obb[r * 4 + 0] = sx1[tid];
                obb[r * 4 + 1] = sy1[tid];
                obb[r * 4 + 2] = sx2[tid];
                obb[r * 4 + 3] = sy2[tid];
            }
        }
    }
    __syncthreads();
    if (tid < POST) {
        out[b * POST + tid]       = oid[tid];
        out[800 + b * POST + tid] = osc[tid];
    }
    if (tid < POST * 4) out[1600 + b * POST * 4 + tid] = obb[tid];
}

// ---------------------------------------------------------------------------
extern "C" void kernel_launch(void* const* d_in, const int* in_sizes, int n_in,
                              void* d_out, int out_size, void* d_ws, size_t ws_size,
                              hipStream_t stream)
{
    const float* tip0 = (const float*)d_in[0];
    const float* tip1 = (const float*)d_in[1];
    const float* tip2 = (const float*)d_in[2];
    const float* anc0 = (const float*)d_in[3];
    const float* anc1 = (const float*)d_in[4];
    const float* anc2 = (const float*)d_in[5];
    float* out = (float*)d_out;

    // ws: hist(8*2048) | cutb(8) | ccnt(8) | flags(8) | ckey(8*CAP) | cidx(8*CAP)
    unsigned* hist  = (unsigned*)d_ws;
    unsigned* cutb  = hist + 8 * NBIN1;
    unsigned* ccnt  = cutb + 8;
    unsigned* flags = ccnt + 8;
    unsigned* ckey  = flags + 8;
    unsigned* cidx  = ckey + (size_t)8 * CAP;

    init_kernel<<<(NBIN1 * 8 + 24 + 255) / 256, 256, 0, stream>>>(hist);

    dim3 g(10, 10, 24);
    score_main<<<g, 256, 0, stream>>>(tip0, tip1, tip2, ccnt, ckey, cidx);
    validate_kernel<<<1, 64, 0, stream>>>(ccnt, flags);
    fb_hist<<<g, 256, 0, stream>>>(tip0, tip1, tip2, hist, flags);
    fb_cut<<<8, 256, 0, stream>>>(hist, cutb, flags);
    fb_compact<<<g, 256, 0, stream>>>(tip0, tip1, tip2, cutb, ccnt, ckey, cidx, flags);
    nms_kernel<<<8, 512, 0, stream>>>(tip0, tip1, tip2, anc0, anc1, anc2,
                                      ckey, cidx, ccnt, out);
}